// Round 1
// baseline (1394.746 us; speedup 1.0000x reference)
//
#include <hip/hip_runtime.h>
#include <math.h>

// Problem constants (B=4, T_p=T_f=8, S=256, d=512, heads=8)
#define BB   4
#define SS   256
#define DD   512
#define HH   8
#define HD   64
#define HALF 32
#define TT   32      // total tokens per sequence
#define TV   16      // vp+vf tokens (vary per (b,s))
#define TA   16      // ap+af tokens (vary per b only)
#define W3   1536    // 3*d

#define VP_BASE 0
#define VF_BASE 4194304      // 4*8*256*512
#define AP_BASE 8388608      // 2*4194304
#define AF_BASE 8404992      // AP_BASE + 4*8*512

#define LN10000_OVER_HALF (9.210340371976184f / 32.0f)

__device__ __forceinline__ float ropefreq(int i) {
    // 10000^(-i/32)
    return __expf(-(float)i * LN10000_OVER_HALF);
}

// ---------------------------------------------------------------------------
// Kernel 1: QKV + RoPE for the 64 unique a-token rows (dedup across S).
// grid=64 blocks (one per (b, t') row), block=256
// ---------------------------------------------------------------------------
__global__ __launch_bounds__(256)
void qkv_a_kernel(const float* __restrict__ a_p, const float* __restrict__ a_f,
                  const float* __restrict__ Wqkv, float* __restrict__ qkv_a) {
    __shared__ float tok[DD];
    __shared__ float row[W3];
    const int r = blockIdx.x;            // 0..63
    const int b = r >> 4, t = r & 15;    // t in [0,16): 0..7 -> a_p, 8..15 -> a_f
    const int pos = 16 + t;              // token position in the 32-seq
    const float* src = (t < 8) ? (a_p + (b * 8 + t) * DD)
                               : (a_f + (b * 8 + (t - 8)) * DD);
    const int tid = threadIdx.x;

    for (int i = tid; i < DD; i += 256) tok[i] = src[i];
    __syncthreads();

    for (int jj = 0; jj < 6; ++jj) {
        int j = jj * 256 + tid;
        float acc = 0.f;
        for (int k = 0; k < DD; ++k) acc += tok[k] * Wqkv[k * W3 + j];
        row[j] = acc;
    }
    __syncthreads();

    // RoPE on q (cols [0,512)) and k (cols [512,1024)); each thread owns a
    // (x1, x2) pair so no extra sync needed before writing.
    for (int idx = tid; idx < 2 * HH * HALF; idx += 256) {  // 512 pairs
        int m   = idx >> 8;              // 0=q, 1=k   (idx / 256)
        int rem = idx & 255;
        int h = rem >> 5, i = rem & 31;
        int base = m * DD + h * HD;
        float x1 = row[base + i], x2 = row[base + i + HALF];
        float ang = (float)pos * ropefreq(i);
        float cc = cosf(ang), ss = sinf(ang);
        row[base + i]        = x1 * cc - x2 * ss;
        row[base + i + HALF] = x2 * cc + x1 * ss;
    }
    __syncthreads();

    for (int j = tid; j < W3; j += 256) qkv_a[r * W3 + j] = row[j];
}

// ---------------------------------------------------------------------------
// Kernel 2: fused per-(b,s) QKV (v-rows) + RoPE + 8-head 32x32 attention.
// Writes pre-projection outputs: v-rows -> attn_v, a-rows -> atomicAdd a_sum.
// grid=1024 (one per (b,s)), block=256.  LDS ~62 KB.
// ---------------------------------------------------------------------------
__global__ __launch_bounds__(256)
void attn_kernel(const float* __restrict__ v_p, const float* __restrict__ v_f,
                 const float* __restrict__ Wqkv, const float* __restrict__ qkv_a,
                 float* __restrict__ attn_v, float* __restrict__ a_sum) {
    __shared__ float tok[TV][DD];            // 32 KB, float4-aligned rows
    __shared__ float qh[TT][HD + 1];         // pad 65 -> conflict-free
    __shared__ float kh[TT][HD + 1];
    __shared__ float vh[TT][HD + 1];
    __shared__ float P[TT][TT + 1];          // scores / probs

    const int bs = blockIdx.x;
    const int b = bs >> 8, s = bs & 255;
    const int tid = threadIdx.x;

    // Stage the 16 v-token rows (coalesced float4).
    for (int idx = tid; idx < TV * (DD / 4); idx += 256) {
        int t = idx >> 7, c4 = idx & 127;
        const float* src = (t < 8) ? (v_p + ((size_t)((b * 8 + t) * SS + s)) * DD)
                                   : (v_f + ((size_t)((b * 8 + t - 8) * SS + s)) * DD);
        ((float4*)&tok[t][0])[c4] = ((const float4*)src)[c4];
    }
    __syncthreads();

    for (int h = 0; h < HH; ++h) {
        // (a1) QKV for the 16 v-rows, this head only: 192 threads, one output
        // column each (m = q/k/v, c = dim-in-head), 16 row-accumulators.
        if (tid < 192) {
            int m = tid >> 6, c = tid & 63;
            int j = m * DD + h * HD + c;
            float acc[TV];
#pragma unroll
            for (int t = 0; t < TV; ++t) acc[t] = 0.f;
            for (int k4 = 0; k4 < DD / 4; ++k4) {
                float w0 = Wqkv[(k4 * 4 + 0) * W3 + j];
                float w1 = Wqkv[(k4 * 4 + 1) * W3 + j];
                float w2 = Wqkv[(k4 * 4 + 2) * W3 + j];
                float w3 = Wqkv[(k4 * 4 + 3) * W3 + j];
#pragma unroll
                for (int t = 0; t < TV; ++t) {
                    float4 tv = ((const float4*)&tok[t][0])[k4];  // wave-broadcast
                    acc[t] += tv.x * w0 + tv.y * w1 + tv.z * w2 + tv.w * w3;
                }
            }
            float* dst = (m == 0) ? &qh[0][0] : (m == 1) ? &kh[0][0] : &vh[0][0];
#pragma unroll
            for (int t = 0; t < TV; ++t) dst[t * (HD + 1) + c] = acc[t];
        }
        // (a2) load the 16 a-rows for this head (already RoPE'd in kernel 1).
        for (int idx = tid; idx < TA * HD; idx += 256) {
            int t = idx >> 6, c = idx & 63;
            const float* base = qkv_a + (size_t)(b * 16 + t) * W3 + h * HD + c;
            qh[16 + t][c] = base[0];
            kh[16 + t][c] = base[DD];
            vh[16 + t][c] = base[2 * DD];
        }
        __syncthreads();

        // (a3) RoPE on v-rows of qh/kh (positions 0..15).
        for (int idx = tid; idx < 2 * TV * HALF; idx += 256) {  // 1024 pairs
            int m = idx >> 9, rem = idx & 511;
            int t = rem >> 5, i = rem & 31;
            float* mat = m ? &kh[0][0] : &qh[0][0];
            float x1 = mat[t * (HD + 1) + i];
            float x2 = mat[t * (HD + 1) + i + HALF];
            float ang = (float)t * ropefreq(i);
            float cc = cosf(ang), ss = sinf(ang);
            mat[t * (HD + 1) + i]        = x1 * cc - x2 * ss;
            mat[t * (HD + 1) + i + HALF] = x2 * cc + x1 * ss;
        }
        __syncthreads();

        // (b) scores S = scale * q k^T : thread -> (i = tid/8, 4 j's)
        {
            int i = tid >> 3, jg = tid & 7;
            float a0 = 0.f, a1 = 0.f, a2 = 0.f, a3 = 0.f;
            for (int c = 0; c < HD; ++c) {
                float q = qh[i][c];
                a0 += q * kh[jg * 4 + 0][c];
                a1 += q * kh[jg * 4 + 1][c];
                a2 += q * kh[jg * 4 + 2][c];
                a3 += q * kh[jg * 4 + 3][c];
            }
            P[i][jg * 4 + 0] = a0 * 0.125f;
            P[i][jg * 4 + 1] = a1 * 0.125f;
            P[i][jg * 4 + 2] = a2 * 0.125f;
            P[i][jg * 4 + 3] = a3 * 0.125f;
        }
        __syncthreads();

        // softmax: one owner thread per query row
        if (tid < TT) {
            float mx = -1e30f;
            for (int j = 0; j < TT; ++j) mx = fmaxf(mx, P[tid][j]);
            float sum = 0.f;
            for (int j = 0; j < TT; ++j) {
                float e = __expf(P[tid][j] - mx);
                P[tid][j] = e;
                sum += e;
            }
            float inv = 1.f / sum;
            for (int j = 0; j < TT; ++j) P[tid][j] *= inv;
        }
        __syncthreads();

        // (c) O = P @ V : wave w handles rows i = w, w+4, ...
        {
            int w = tid >> 6, c = tid & 63;
            for (int i = w; i < TT; i += 4) {
                float acc = 0.f;
                for (int j = 0; j < TT; ++j) acc += P[i][j] * vh[j][c];
                if (i < TV) {
                    attn_v[((size_t)bs * TV + i) * DD + h * HD + c] = acc;
                } else {
                    atomicAdd(&a_sum[(size_t)(b * TA + (i - 16)) * DD + h * HD + c], acc);
                }
            }
        }
        __syncthreads();  // LDS reused next head
    }
}

// ---------------------------------------------------------------------------
// Kernel 3: out-projection for v-rows + scatter to vp_o / vf_o.
// grid=1024 (one per (b,s)), block=256.
// ---------------------------------------------------------------------------
__global__ __launch_bounds__(256)
void proj_v_kernel(const float* __restrict__ attn_v, const float* __restrict__ Wp,
                   const float* __restrict__ bp, float* __restrict__ out) {
    __shared__ float A[TV][DD];  // 32 KB
    const int bs = blockIdx.x;
    const int b = bs >> 8, s = bs & 255;
    const int tid = threadIdx.x;

    for (int idx = tid; idx < TV * (DD / 4); idx += 256) {
        int t = idx >> 7, c4 = idx & 127;
        ((float4*)&A[t][0])[c4] =
            ((const float4*)(attn_v + ((size_t)bs * TV + t) * DD))[c4];
    }
    __syncthreads();

    for (int jj = 0; jj < 2; ++jj) {
        int j = jj * 256 + tid;
        float acc[TV];
#pragma unroll
        for (int t = 0; t < TV; ++t) acc[t] = 0.f;
        for (int k4 = 0; k4 < DD / 4; ++k4) {
            float w0 = Wp[(k4 * 4 + 0) * DD + j];
            float w1 = Wp[(k4 * 4 + 1) * DD + j];
            float w2 = Wp[(k4 * 4 + 2) * DD + j];
            float w3 = Wp[(k4 * 4 + 3) * DD + j];
#pragma unroll
            for (int t = 0; t < TV; ++t) {
                float4 av = ((const float4*)&A[t][0])[k4];  // wave-broadcast
                acc[t] += av.x * w0 + av.y * w1 + av.z * w2 + av.w * w3;
            }
        }
        float bias = bp[j];
#pragma unroll
        for (int t = 0; t < TV; ++t) {
            size_t off = (t < 8)
                ? (VP_BASE + ((size_t)((b * 8 + t) * SS + s)) * DD + j)
                : (VF_BASE + ((size_t)((b * 8 + t - 8) * SS + s)) * DD + j);
            out[off] = acc[t] + bias;
        }
    }
}

// ---------------------------------------------------------------------------
// Kernel 4: mean-over-S (via a_sum/256) + projection for the 64 a-rows.
// grid=64, block=256.
// ---------------------------------------------------------------------------
__global__ __launch_bounds__(256)
void proj_a_kernel(const float* __restrict__ a_sum, const float* __restrict__ Wp,
                   const float* __restrict__ bp, float* __restrict__ out) {
    __shared__ float arow[DD];
    const int r = blockIdx.x;            // 0..63
    const int b = r >> 4, t = r & 15;
    const int tid = threadIdx.x;

    for (int i = tid; i < DD; i += 256)
        arow[i] = a_sum[(size_t)r * DD + i] * (1.0f / (float)SS);
    __syncthreads();

    for (int jj = 0; jj < 2; ++jj) {
        int j = jj * 256 + tid;
        float acc = bp[j];
        for (int k = 0; k < DD; ++k) acc += arow[k] * Wp[k * DD + j];
        size_t off = (t < 8) ? (AP_BASE + (size_t)(b * 8 + t) * DD + j)
                             : (AF_BASE + (size_t)(b * 8 + (t - 8)) * DD + j);
        out[off] = acc;
    }
}

// ---------------------------------------------------------------------------
extern "C" void kernel_launch(void* const* d_in, const int* in_sizes, int n_in,
                              void* d_out, int out_size, void* d_ws, size_t ws_size,
                              hipStream_t stream) {
    const float* v_p  = (const float*)d_in[0];
    const float* v_f  = (const float*)d_in[1];
    const float* a_p  = (const float*)d_in[2];
    const float* a_f  = (const float*)d_in[3];
    const float* Wqkv = (const float*)d_in[4];
    const float* Wp   = (const float*)d_in[5];
    const float* bp   = (const float*)d_in[6];
    float* out = (float*)d_out;

    // Workspace layout (fp32), total ~34.1 MB:
    float* ws     = (float*)d_ws;
    float* qkv_a  = ws;                              // 64*1536
    float* a_sum  = ws + 64 * W3;                    // 64*512
    float* attn_v = ws + 64 * W3 + 64 * DD;          // 1024*16*512

    hipMemsetAsync(a_sum, 0, 64 * DD * sizeof(float), stream);
    qkv_a_kernel<<<64, 256, 0, stream>>>(a_p, a_f, Wqkv, qkv_a);
    attn_kernel<<<1024, 256, 0, stream>>>(v_p, v_f, Wqkv, qkv_a, attn_v, a_sum);
    proj_v_kernel<<<1024, 256, 0, stream>>>(attn_v, Wp, bp, out);
    proj_a_kernel<<<64, 256, 0, stream>>>(a_sum, Wp, bp, out);
}

// Round 2
// 459.412 us; speedup vs baseline: 3.0359x; 3.0359x over previous
//
#include <hip/hip_runtime.h>
#include <math.h>

// Problem constants (B=4, T_p=T_f=8, S=256, d=512, heads=8)
#define BB   4
#define SS   256
#define DD   512
#define HH   8
#define HD   64
#define HALF 32
#define TT   32      // total tokens per sequence
#define TV   16      // vp+vf tokens (vary per (b,s))
#define TA   16      // ap+af tokens (vary per b only)
#define W3   1536    // 3*d
#define MROWS 16384  // 1024 (b,s) * 16 v-tokens

#define VP_BASE 0
#define VF_BASE 4194304      // 4*8*256*512
#define AP_BASE 8388608      // 2*4194304
#define AF_BASE 8404992      // AP_BASE + 4*8*512

#define LN10000_OVER_HALF (9.210340371976184f / 32.0f)

typedef _Float16 h4 __attribute__((ext_vector_type(4)));
typedef _Float16 h8 __attribute__((ext_vector_type(8)));
typedef float    f4 __attribute__((ext_vector_type(4)));

__device__ __forceinline__ float ropefreq(int i) {
    return __expf(-(float)i * LN10000_OVER_HALF);   // 10000^(-i/32)
}

// async global->LDS, 16 bytes per lane (global_load_lds_dwordx4)
typedef __attribute__((address_space(3))) void*       lds_ptr_t;
typedef const __attribute__((address_space(1))) void* gbl_ptr_t;
__device__ __forceinline__ void async16(const void* g, void* l) {
    __builtin_amdgcn_global_load_lds((gbl_ptr_t)g, (lds_ptr_t)l, 16, 0, 0);
}

// ---------------------------------------------------------------------------
// Kernel: gather v-tokens into token-ordered fp16 matrix tok[16384][512].
// row r: bs=r/16, t=r%16; b=bs>>8, s=bs&255; t<8 -> v_p, else v_f.
// ---------------------------------------------------------------------------
__global__ __launch_bounds__(256)
void conv_tok_kernel(const float* __restrict__ v_p, const float* __restrict__ v_f,
                     _Float16* __restrict__ tok) {
    int id = blockIdx.x * 256 + threadIdx.x;        // 2,097,152 threads
    int e  = id * 4;                                // element index
    int r  = e >> 9, c = e & 511;
    int bs = r >> 4, t = r & 15, b = bs >> 8, s = bs & 255;
    const float* src = (t < 8) ? v_p + (size_t)((b * 8 + t) * SS + s) * DD
                               : v_f + (size_t)((b * 8 + t - 8) * SS + s) * DD;
    float4 v = *(const float4*)(src + c);
    h4 o = { (_Float16)v.x, (_Float16)v.y, (_Float16)v.z, (_Float16)v.w };
    *(h4*)(tok + (size_t)r * DD + c) = o;
}

// ---------------------------------------------------------------------------
// Kernel: transpose+convert weights to fp16, K-major for MFMA B-frag loads.
// Wt[n][k] = Wqkv[k][n]  (1536x512);  Wpt[n][k] = Wp[k][n]  (512x512)
// ---------------------------------------------------------------------------
__global__ __launch_bounds__(256)
void conv_w_kernel(const float* __restrict__ Wqkv, const float* __restrict__ Wp,
                   _Float16* __restrict__ Wt, _Float16* __restrict__ Wpt) {
    int id = blockIdx.x * 256 + threadIdx.x;        // 1,048,576 threads
    if (id < W3 * DD) {
        int n = id >> 9, k = id & 511;
        Wt[id] = (_Float16)Wqkv[k * W3 + n];
    } else {
        int id2 = id - W3 * DD;
        int n = id2 >> 9, k = id2 & 511;
        Wpt[id2] = (_Float16)Wp[k * DD + n];
    }
}

// ---------------------------------------------------------------------------
// Kernel: QKV + RoPE for the 64 unique a-token rows (fp32, dedup across S).
// ---------------------------------------------------------------------------
__global__ __launch_bounds__(256)
void qkv_a_kernel(const float* __restrict__ a_p, const float* __restrict__ a_f,
                  const float* __restrict__ Wqkv, float* __restrict__ qkv_a) {
    __shared__ float tokr[DD];
    __shared__ float row[W3];
    const int r = blockIdx.x;            // 0..63
    const int b = r >> 4, t = r & 15;
    const int pos = 16 + t;
    const float* src = (t < 8) ? (a_p + (b * 8 + t) * DD)
                               : (a_f + (b * 8 + (t - 8)) * DD);
    const int tid = threadIdx.x;

    for (int i = tid; i < DD; i += 256) tokr[i] = src[i];
    __syncthreads();

    for (int jj = 0; jj < 6; ++jj) {
        int j = jj * 256 + tid;
        float acc = 0.f;
        for (int k = 0; k < DD; ++k) acc += tokr[k] * Wqkv[k * W3 + j];
        row[j] = acc;
    }
    __syncthreads();

    for (int idx = tid; idx < 2 * HH * HALF; idx += 256) {  // 512 (x1,x2) pairs
        int m   = idx >> 8;
        int rem = idx & 255;
        int h = rem >> 5, i = rem & 31;
        int base = m * DD + h * HD;
        float x1 = row[base + i], x2 = row[base + i + HALF];
        float ang = (float)pos * ropefreq(i);
        float cc = cosf(ang), ss = sinf(ang);
        row[base + i]        = x1 * cc - x2 * ss;
        row[base + i + HALF] = x2 * cc + x1 * ss;
    }
    __syncthreads();

    for (int j = tid; j < W3; j += 256) qkv_a[r * W3 + j] = row[j];
}

// ---------------------------------------------------------------------------
// MFMA GEMM 1: qkv[16384][1536] = tok[16384][512] @ Wqkv  (fp16 in, fp16 out)
// m97 structure: 128x128 tile, BK=32, 4 waves of 4x4 16x16x32 MFMAs.
// grid (128, 12), block 256.
// ---------------------------------------------------------------------------
__global__ __launch_bounds__(256)
void gemm_qkv_kernel(const _Float16* __restrict__ A, const _Float16* __restrict__ Bt,
                     _Float16* __restrict__ C) {
    __shared__ __align__(16) _Float16 As[128 * 32];   // [m][k] row-major, 8 KB
    __shared__ __align__(16) _Float16 Bs[128 * 32];   // [n][k] row-major, 8 KB
    const int tid = threadIdx.x, lane = tid & 63, wave = tid >> 6;
    const int tm = blockIdx.x, tn = blockIdx.y;
    const int m_base = (wave >> 1) * 64, n_base = (wave & 1) * 64;
    const int quad = lane >> 4, l16 = lane & 15;

    f4 acc[4][4] = {};

    for (int k0 = 0; k0 < 512; k0 += 32) {
#pragma unroll
        for (int rnd = 0; rnd < 2; ++rnd) {
            int i = rnd * 256 + tid;                 // chunk id in [0,512)
            int r = i >> 2, c = (i & 3) * 8;
            async16(A  + (size_t)(tm * 128 + r) * 512 + k0 + c, &As[i * 8]);
            async16(Bt + (size_t)(tn * 128 + r) * 512 + k0 + c, &Bs[i * 8]);
        }
        __syncthreads();

        h8 af[4], bf[4];
#pragma unroll
        for (int mi = 0; mi < 4; ++mi)
            af[mi] = *(const h8*)&As[(m_base + mi * 16 + l16) * 32 + quad * 8];
#pragma unroll
        for (int ni = 0; ni < 4; ++ni)
            bf[ni] = *(const h8*)&Bs[(n_base + ni * 16 + l16) * 32 + quad * 8];
#pragma unroll
        for (int mi = 0; mi < 4; ++mi)
#pragma unroll
            for (int ni = 0; ni < 4; ++ni)
                acc[mi][ni] = __builtin_amdgcn_mfma_f32_16x16x32_f16(
                    af[mi], bf[ni], acc[mi][ni], 0, 0, 0);
        __syncthreads();
    }

    // C/D layout: col = lane&15, row = quad*4 + reg (guide §3, m89-verified)
#pragma unroll
    for (int mi = 0; mi < 4; ++mi)
#pragma unroll
        for (int ni = 0; ni < 4; ++ni) {
            int row = tm * 128 + m_base + mi * 16 + quad * 4;
            int col = tn * 128 + n_base + ni * 16 + l16;
#pragma unroll
            for (int r = 0; r < 4; ++r)
                C[(size_t)(row + r) * W3 + col] = (_Float16)acc[mi][ni][r];
        }
}

// ---------------------------------------------------------------------------
// Attention kernel (fp32 math): per (b,s), loop 8 heads.
// Reads qkv (fp16) for v-rows + qkv_a (fp32, already RoPE'd) for a-rows.
// RoPE v-rows, 32x32 scores, softmax, PV. v-rows -> attnv (fp16);
// a-rows -> atomicAdd a_sum (fp32).
// ---------------------------------------------------------------------------
__global__ __launch_bounds__(256)
void attn2_kernel(const _Float16* __restrict__ qkv, const float* __restrict__ qkv_a,
                  _Float16* __restrict__ attnv, float* __restrict__ a_sum) {
    __shared__ float qh[TT][HD + 1];
    __shared__ float kh[TT][HD + 1];
    __shared__ float vh[TT][HD + 1];
    __shared__ float P[TT][TT + 1];
    const int bs = blockIdx.x, b = bs >> 8;
    const int tid = threadIdx.x;

    for (int h = 0; h < HH; ++h) {
        // load this head's q/k/v for all 32 tokens
        for (int idx = tid; idx < 3 * TT * HD; idx += 256) {   // 6144
            int m = idx >> 11, rem = idx & 2047;
            int t = rem >> 6, c = rem & 63;
            float val;
            if (t < TV)
                val = (float)qkv[(size_t)(bs * 16 + t) * W3 + m * DD + h * HD + c];
            else
                val = qkv_a[(size_t)(b * 16 + (t - 16)) * W3 + m * DD + h * HD + c];
            float* dst = (m == 0) ? &qh[0][0] : (m == 1) ? &kh[0][0] : &vh[0][0];
            dst[t * (HD + 1) + c] = val;
        }
        __syncthreads();

        // RoPE on v-rows (positions 0..15)
        for (int idx = tid; idx < 2 * TV * HALF; idx += 256) {  // 1024 pairs
            int m = idx >> 9, rem = idx & 511;
            int t = rem >> 5, i = rem & 31;
            float* mat = m ? &kh[0][0] : &qh[0][0];
            float x1 = mat[t * (HD + 1) + i];
            float x2 = mat[t * (HD + 1) + i + HALF];
            float ang = (float)t * ropefreq(i);
            float cc = cosf(ang), ss = sinf(ang);
            mat[t * (HD + 1) + i]        = x1 * cc - x2 * ss;
            mat[t * (HD + 1) + i + HALF] = x2 * cc + x1 * ss;
        }
        __syncthreads();

        // scores
        {
            int i = tid >> 3, jg = tid & 7;
            float a0 = 0.f, a1 = 0.f, a2 = 0.f, a3 = 0.f;
            for (int c = 0; c < HD; ++c) {
                float q = qh[i][c];
                a0 += q * kh[jg * 4 + 0][c];
                a1 += q * kh[jg * 4 + 1][c];
                a2 += q * kh[jg * 4 + 2][c];
                a3 += q * kh[jg * 4 + 3][c];
            }
            P[i][jg * 4 + 0] = a0 * 0.125f;
            P[i][jg * 4 + 1] = a1 * 0.125f;
            P[i][jg * 4 + 2] = a2 * 0.125f;
            P[i][jg * 4 + 3] = a3 * 0.125f;
        }
        __syncthreads();

        if (tid < TT) {
            float mx = -1e30f;
            for (int j = 0; j < TT; ++j) mx = fmaxf(mx, P[tid][j]);
            float sum = 0.f;
            for (int j = 0; j < TT; ++j) {
                float e = __expf(P[tid][j] - mx);
                P[tid][j] = e;
                sum += e;
            }
            float inv = 1.f / sum;
            for (int j = 0; j < TT; ++j) P[tid][j] *= inv;
        }
        __syncthreads();

        // PV
        {
            int w = tid >> 6, c = tid & 63;
            for (int i = w; i < TT; i += 4) {
                float acc = 0.f;
                for (int j = 0; j < TT; ++j) acc += P[i][j] * vh[j][c];
                if (i < TV)
                    attnv[(size_t)(bs * 16 + i) * DD + h * HD + c] = (_Float16)acc;
                else
                    atomicAdd(&a_sum[(size_t)(b * 16 + (i - 16)) * DD + h * HD + c], acc);
            }
        }
        __syncthreads();
    }
}

// ---------------------------------------------------------------------------
// MFMA GEMM 2: out_v = attnv[16384][512] @ Wp + bias, scattered to vp_o/vf_o.
// grid (128, 4), block 256.
// ---------------------------------------------------------------------------
__global__ __launch_bounds__(256)
void gemm_proj_kernel(const _Float16* __restrict__ A, const _Float16* __restrict__ Bt,
                      const float* __restrict__ bp, float* __restrict__ out) {
    __shared__ __align__(16) _Float16 As[128 * 32];
    __shared__ __align__(16) _Float16 Bs[128 * 32];
    const int tid = threadIdx.x, lane = tid & 63, wave = tid >> 6;
    const int tm = blockIdx.x, tn = blockIdx.y;
    const int m_base = (wave >> 1) * 64, n_base = (wave & 1) * 64;
    const int quad = lane >> 4, l16 = lane & 15;

    f4 acc[4][4] = {};

    for (int k0 = 0; k0 < 512; k0 += 32) {
#pragma unroll
        for (int rnd = 0; rnd < 2; ++rnd) {
            int i = rnd * 256 + tid;
            int r = i >> 2, c = (i & 3) * 8;
            async16(A  + (size_t)(tm * 128 + r) * 512 + k0 + c, &As[i * 8]);
            async16(Bt + (size_t)(tn * 128 + r) * 512 + k0 + c, &Bs[i * 8]);
        }
        __syncthreads();

        h8 af[4], bf[4];
#pragma unroll
        for (int mi = 0; mi < 4; ++mi)
            af[mi] = *(const h8*)&As[(m_base + mi * 16 + l16) * 32 + quad * 8];
#pragma unroll
        for (int ni = 0; ni < 4; ++ni)
            bf[ni] = *(const h8*)&Bs[(n_base + ni * 16 + l16) * 32 + quad * 8];
#pragma unroll
        for (int mi = 0; mi < 4; ++mi)
#pragma unroll
            for (int ni = 0; ni < 4; ++ni)
                acc[mi][ni] = __builtin_amdgcn_mfma_f32_16x16x32_f16(
                    af[mi], bf[ni], acc[mi][ni], 0, 0, 0);
        __syncthreads();
    }

#pragma unroll
    for (int mi = 0; mi < 4; ++mi)
#pragma unroll
        for (int ni = 0; ni < 4; ++ni) {
            int row0 = tm * 128 + m_base + mi * 16 + quad * 4;
            int col  = tn * 128 + n_base + ni * 16 + l16;
            float bias = bp[col];
#pragma unroll
            for (int r = 0; r < 4; ++r) {
                int row = row0 + r;
                int bsq = row >> 4, t = row & 15;
                int b = bsq >> 8, s = bsq & 255;
                size_t off = (t < 8)
                    ? (VP_BASE + (size_t)((b * 8 + t) * SS + s) * DD + col)
                    : (VF_BASE + (size_t)((b * 8 + t - 8) * SS + s) * DD + col);
                out[off] = acc[mi][ni][r] + bias;
            }
        }
}

// ---------------------------------------------------------------------------
// Kernel: mean-over-S (a_sum/256) + fp32 projection for the 64 a-rows.
// ---------------------------------------------------------------------------
__global__ __launch_bounds__(256)
void proj_a_kernel(const float* __restrict__ a_sum, const float* __restrict__ Wp,
                   const float* __restrict__ bp, float* __restrict__ out) {
    __shared__ float arow[DD];
    const int r = blockIdx.x;            // 0..63
    const int b = r >> 4, t = r & 15;
    const int tid = threadIdx.x;

    for (int i = tid; i < DD; i += 256)
        arow[i] = a_sum[(size_t)r * DD + i] * (1.0f / (float)SS);
    __syncthreads();

    for (int jj = 0; jj < 2; ++jj) {
        int j = jj * 256 + tid;
        float acc = bp[j];
        for (int k = 0; k < DD; ++k) acc += arow[k] * Wp[k * DD + j];
        size_t off = (t < 8) ? (AP_BASE + (size_t)(b * 8 + t) * DD + j)
                             : (AF_BASE + (size_t)(b * 8 + (t - 8)) * DD + j);
        out[off] = acc;
    }
}

// ---------------------------------------------------------------------------
extern "C" void kernel_launch(void* const* d_in, const int* in_sizes, int n_in,
                              void* d_out, int out_size, void* d_ws, size_t ws_size,
                              hipStream_t stream) {
    const float* v_p  = (const float*)d_in[0];
    const float* v_f  = (const float*)d_in[1];
    const float* a_p  = (const float*)d_in[2];
    const float* a_f  = (const float*)d_in[3];
    const float* Wqkv = (const float*)d_in[4];
    const float* Wp   = (const float*)d_in[5];
    const float* bp   = (const float*)d_in[6];
    float* out = (float*)d_out;

    // Workspace layout (~86.5 MB)
    char* w = (char*)d_ws;
    _Float16* tok   = (_Float16*)w;  w += (size_t)MROWS * DD * 2;   // 16.78 MB
    _Float16* qkv   = (_Float16*)w;  w += (size_t)MROWS * W3 * 2;   // 50.33 MB
    _Float16* attnv = (_Float16*)w;  w += (size_t)MROWS * DD * 2;   // 16.78 MB
    _Float16* Wt    = (_Float16*)w;  w += (size_t)W3 * DD * 2;      //  1.57 MB
    _Float16* Wpt   = (_Float16*)w;  w += (size_t)DD * DD * 2;      //  0.52 MB
    float*    qkv_a = (float*)w;     w += (size_t)64 * W3 * 4;      //  0.39 MB
    float*    a_sum = (float*)w;     w += (size_t)64 * DD * 4;      //  0.13 MB

    hipMemsetAsync(a_sum, 0, 64 * DD * sizeof(float), stream);
    conv_tok_kernel<<<8192, 256, 0, stream>>>(v_p, v_f, tok);
    conv_w_kernel<<<4096, 256, 0, stream>>>(Wqkv, Wp, Wt, Wpt);
    qkv_a_kernel<<<64, 256, 0, stream>>>(a_p, a_f, Wqkv, qkv_a);
    gemm_qkv_kernel<<<dim3(128, 12), 256, 0, stream>>>(tok, Wt, qkv);
    attn2_kernel<<<1024, 256, 0, stream>>>(qkv, qkv_a, attnv, a_sum);
    gemm_proj_kernel<<<dim3(128, 4), 256, 0, stream>>>(attnv, Wpt, bp, out);
    proj_a_kernel<<<64, 256, 0, stream>>>(a_sum, Wp, bp, out);
}

// Round 3
// 258.353 us; speedup vs baseline: 5.3986x; 1.7782x over previous
//
#include <hip/hip_runtime.h>
#include <math.h>

// Problem constants (B=4, T_p=T_f=8, S=256, d=512, heads=8)
#define BB   4
#define SS   256
#define DD   512
#define HH   8
#define HD   64
#define HALF 32
#define TT   32      // total tokens per sequence
#define TV   16      // vp+vf tokens (vary per (b,s))
#define W3   1536    // 3*d
#define MROWS  16448 // 16384 v-rows + 64 unique a-rows
#define MPAD   16512 // 129 * 128

#define VP_BASE 0
#define VF_BASE 4194304      // 4*8*256*512
#define AP_BASE 8388608      // 2*4194304
#define AF_BASE 8404992      // AP_BASE + 4*8*512

#define LN10000_OVER_HALF (9.210340371976184f / 32.0f)

typedef _Float16 h4 __attribute__((ext_vector_type(4)));
typedef _Float16 h8 __attribute__((ext_vector_type(8)));
typedef float    f4 __attribute__((ext_vector_type(4)));
typedef float    f16v __attribute__((ext_vector_type(16)));

__device__ __forceinline__ float ropefreq(int i) {
    return __expf(-(float)i * LN10000_OVER_HALF);   // 10000^(-i/32)
}

// async global->LDS, 16 bytes per lane (global_load_lds_dwordx4)
typedef __attribute__((address_space(3))) void*       lds_ptr_t;
typedef const __attribute__((address_space(1))) void* gbl_ptr_t;
__device__ __forceinline__ void async16(const void* g, void* l) {
    __builtin_amdgcn_global_load_lds((gbl_ptr_t)g, (lds_ptr_t)l, 16, 0, 0);
}

// ---------------------------------------------------------------------------
// Gather tokens into fp16 matrix tok[16512][512].
// rows 0..16383: v-tokens (bs = r/16, t = r%16); rows 16384..16447: a-tokens.
// ---------------------------------------------------------------------------
__global__ __launch_bounds__(256)
void conv_tok_kernel(const float* __restrict__ v_p, const float* __restrict__ v_f,
                     const float* __restrict__ a_p, const float* __restrict__ a_f,
                     _Float16* __restrict__ tok) {
    int id = blockIdx.x * 256 + threadIdx.x;        // 2,105,344 threads
    int e  = id * 4;
    int r  = e >> 9, c = e & 511;
    const float* src;
    if (r < 16384) {
        int bs = r >> 4, t = r & 15, b = bs >> 8, s = bs & 255;
        src = (t < 8) ? v_p + (size_t)((b * 8 + t) * SS + s) * DD
                      : v_f + (size_t)((b * 8 + t - 8) * SS + s) * DD;
    } else {
        int idx = r - 16384, b = idx >> 4, t2 = idx & 15;
        src = (t2 < 8) ? a_p + (size_t)(b * 8 + t2) * DD
                       : a_f + (size_t)(b * 8 + (t2 - 8)) * DD;
    }
    float4 v = *(const float4*)(src + c);
    h4 o = { (_Float16)v.x, (_Float16)v.y, (_Float16)v.z, (_Float16)v.w };
    *(h4*)(tok + (size_t)r * DD + c) = o;
}

// ---------------------------------------------------------------------------
// Transpose+convert weights to fp16 (K-major for MFMA B-frag loads).
// ---------------------------------------------------------------------------
__global__ __launch_bounds__(256)
void conv_w_kernel(const float* __restrict__ Wqkv, const float* __restrict__ Wp,
                   _Float16* __restrict__ Wt, _Float16* __restrict__ Wpt) {
    int id = blockIdx.x * 256 + threadIdx.x;        // 1,048,576 threads
    if (id < W3 * DD) {
        int n = id >> 9, k = id & 511;
        Wt[id] = (_Float16)Wqkv[k * W3 + n];
    } else {
        int id2 = id - W3 * DD;
        int n = id2 >> 9, k = id2 & 511;
        Wpt[id2] = (_Float16)Wp[k * DD + n];
    }
}

// ---------------------------------------------------------------------------
// MFMA GEMM 1: qkv[16512][1536] = tok[16512][512] @ Wqkv (fp16 in/out)
// grid (129, 12), block 256.
// ---------------------------------------------------------------------------
__global__ __launch_bounds__(256)
void gemm_qkv_kernel(const _Float16* __restrict__ A, const _Float16* __restrict__ Bt,
                     _Float16* __restrict__ C) {
    __shared__ __align__(16) _Float16 As[128 * 32];
    __shared__ __align__(16) _Float16 Bs[128 * 32];
    const int tid = threadIdx.x, lane = tid & 63, wave = tid >> 6;
    const int tm = blockIdx.x, tn = blockIdx.y;
    const int m_base = (wave >> 1) * 64, n_base = (wave & 1) * 64;
    const int quad = lane >> 4, l16 = lane & 15;

    f4 acc[4][4] = {};

    for (int k0 = 0; k0 < 512; k0 += 32) {
#pragma unroll
        for (int rnd = 0; rnd < 2; ++rnd) {
            int i = rnd * 256 + tid;
            int r = i >> 2, c = (i & 3) * 8;
            async16(A  + (size_t)(tm * 128 + r) * 512 + k0 + c, &As[i * 8]);
            async16(Bt + (size_t)(tn * 128 + r) * 512 + k0 + c, &Bs[i * 8]);
        }
        __syncthreads();

        h8 af[4], bf[4];
#pragma unroll
        for (int mi = 0; mi < 4; ++mi)
            af[mi] = *(const h8*)&As[(m_base + mi * 16 + l16) * 32 + quad * 8];
#pragma unroll
        for (int ni = 0; ni < 4; ++ni)
            bf[ni] = *(const h8*)&Bs[(n_base + ni * 16 + l16) * 32 + quad * 8];
#pragma unroll
        for (int mi = 0; mi < 4; ++mi)
#pragma unroll
            for (int ni = 0; ni < 4; ++ni)
                acc[mi][ni] = __builtin_amdgcn_mfma_f32_16x16x32_f16(
                    af[mi], bf[ni], acc[mi][ni], 0, 0, 0);
        __syncthreads();
    }

#pragma unroll
    for (int mi = 0; mi < 4; ++mi)
#pragma unroll
        for (int ni = 0; ni < 4; ++ni) {
            int row = tm * 128 + m_base + mi * 16 + quad * 4;
            int col = tn * 128 + n_base + ni * 16 + l16;
#pragma unroll
            for (int r = 0; r < 4; ++r)
                C[(size_t)(row + r) * W3 + col] = (_Float16)acc[mi][ni][r];
        }
}

// ---------------------------------------------------------------------------
// MFMA attention: one block per (b,s), 4 waves, wave w handles heads w, w+4.
// Wave-private LDS; no __syncthreads. RoPE in registers (pos = row = lane&31).
// QK^T and PV via v_mfma_f32_32x32x16_f16.
//   A-frag: A[m=lane&31][k=(lane>>5)*8+j]  (B-frag of X^T has same addressing)
//   C/D:    col=lane&31, row=(reg&3)+8*(reg>>2)+4*(lane>>5)
// ---------------------------------------------------------------------------
__global__ __launch_bounds__(256)
void attn3_kernel(const _Float16* __restrict__ qkv, _Float16* __restrict__ attnv,
                  float* __restrict__ a_sum) {
    __shared__ _Float16 VlA[4][32 * 72];   // per-wave V tile, stride 72
    __shared__ _Float16 PlA[4][32 * 40];   // per-wave P tile, stride 40
    const int bs = blockIdx.x, b = bs >> 8;
    const int tid = threadIdx.x, wave = tid >> 6, lane = tid & 63;
    const int t = lane & 31, half = lane >> 5;
    _Float16* vl = &VlA[wave][0];
    _Float16* pl = &PlA[wave][0];

    // this lane's token row in the qkv matrix (a-rows are deduped at 16384+)
    const size_t row = (t < 16) ? (size_t)(bs * 16 + t)
                                : (size_t)(16384 + b * 16 + (t - 16));
    const _Float16* rowp = qkv + row * W3;

    // RoPE cos/sin for this lane (pos = t, freq index = 8*half+j and 16+8*half+j)
    float ccA[8], ssA[8], ccB[8], ssB[8];
#pragma unroll
    for (int j = 0; j < 8; ++j) {
        float aA = (float)t * ropefreq(8 * half + j);
        float aB = (float)t * ropefreq(16 + 8 * half + j);
        __sincosf(aA, &ssA[j], &ccA[j]);
        __sincosf(aB, &ssB[j], &ccB[j]);
    }

    for (int hh = 0; hh < 2; ++hh) {
        const int h = wave + 4 * hh;
        const _Float16* qp = rowp + h * HD;

        // ---- stage V (cols 32*half..+31 of this lane's row) ----
        h8 v0 = *(const h8*)(qp + 2 * DD + 32 * half);
        h8 v1 = *(const h8*)(qp + 2 * DD + 32 * half + 8);
        h8 v2 = *(const h8*)(qp + 2 * DD + 32 * half + 16);
        h8 v3 = *(const h8*)(qp + 2 * DD + 32 * half + 24);
        *(h8*)&vl[t * 72 + 32 * half +  0] = v0;
        *(h8*)&vl[t * 72 + 32 * half +  8] = v1;
        *(h8*)&vl[t * 72 + 32 * half + 16] = v2;
        *(h8*)&vl[t * 72 + 32 * half + 24] = v3;

        // ---- load Q,K chunks (chunk c covers cols 8c..8c+7; lane owns
        //      chunks half, half+2, half+4, half+6; RoPE pairs (c, c+4)) ----
        h8 q0 = *(const h8*)(qp + 8 * half);
        h8 q1 = *(const h8*)(qp + 8 * half + 16);
        h8 q2 = *(const h8*)(qp + 8 * half + 32);
        h8 q3 = *(const h8*)(qp + 8 * half + 48);
        h8 k0 = *(const h8*)(qp + DD + 8 * half);
        h8 k1 = *(const h8*)(qp + DD + 8 * half + 16);
        h8 k2 = *(const h8*)(qp + DD + 8 * half + 32);
        h8 k3 = *(const h8*)(qp + DD + 8 * half + 48);

        h8 qf0, qf1, qf2, qf3, kf0, kf1, kf2, kf3;
#pragma unroll
        for (int j = 0; j < 8; ++j) {
            // Q: fold in softmax scale 1/8
            float x1 = (float)q0[j], x2 = (float)q2[j];
            qf0[j] = (_Float16)(0.125f * (x1 * ccA[j] - x2 * ssA[j]));
            qf2[j] = (_Float16)(0.125f * (x2 * ccA[j] + x1 * ssA[j]));
            x1 = (float)q1[j]; x2 = (float)q3[j];
            qf1[j] = (_Float16)(0.125f * (x1 * ccB[j] - x2 * ssB[j]));
            qf3[j] = (_Float16)(0.125f * (x2 * ccB[j] + x1 * ssB[j]));
            // K: no scale
            x1 = (float)k0[j]; x2 = (float)k2[j];
            kf0[j] = (_Float16)(x1 * ccA[j] - x2 * ssA[j]);
            kf2[j] = (_Float16)(x2 * ccA[j] + x1 * ssA[j]);
            x1 = (float)k1[j]; x2 = (float)k3[j];
            kf1[j] = (_Float16)(x1 * ccB[j] - x2 * ssB[j]);
            kf3[j] = (_Float16)(x2 * ccB[j] + x1 * ssB[j]);
        }

        // ---- scores S = (Q/8) K^T : 4 MFMAs over K=64 ----
        f16v s = {};
        s = __builtin_amdgcn_mfma_f32_32x32x16_f16(qf0, kf0, s, 0, 0, 0);
        s = __builtin_amdgcn_mfma_f32_32x32x16_f16(qf1, kf1, s, 0, 0, 0);
        s = __builtin_amdgcn_mfma_f32_32x32x16_f16(qf2, kf2, s, 0, 0, 0);
        s = __builtin_amdgcn_mfma_f32_32x32x16_f16(qf3, kf3, s, 0, 0, 0);

        // ---- softmax per row (row lives in this lane's 32-lane half) ----
#pragma unroll
        for (int r = 0; r < 16; ++r) {
            float m = s[r];
#pragma unroll
            for (int mask = 1; mask <= 16; mask <<= 1)
                m = fmaxf(m, __shfl_xor(m, mask));
            float e = __expf(s[r] - m);
            float sm = e;
#pragma unroll
            for (int mask = 1; mask <= 16; mask <<= 1)
                sm += __shfl_xor(sm, mask);
            float p = e / sm;
            int rr = (r & 3) + 8 * (r >> 2) + 4 * half;
            pl[rr * 40 + t] = (_Float16)p;
        }

        // ---- O = P V : 2 n-halves x 2 k-steps ----
#pragma unroll
        for (int n0 = 0; n0 < 2; ++n0) {
            f16v o = {};
#pragma unroll
            for (int kk = 0; kk < 2; ++kk) {
                h8 pf = *(const h8*)&pl[t * 40 + kk * 16 + half * 8];
                h8 vf;
#pragma unroll
                for (int jj = 0; jj < 8; ++jj)
                    vf[jj] = vl[(kk * 16 + half * 8 + jj) * 72 + n0 * 32 + t];
                o = __builtin_amdgcn_mfma_f32_32x32x16_f16(pf, vf, o, 0, 0, 0);
            }
            const int col = n0 * 32 + t;
#pragma unroll
            for (int r = 0; r < 16; ++r) {
                int i = (r & 3) + 8 * (r >> 2) + 4 * half;
                if (i < TV)
                    attnv[(size_t)(bs * 16 + i) * DD + h * HD + col] = (_Float16)o[r];
                else
                    atomicAdd(&a_sum[(size_t)(b * 16 + (i - 16)) * DD + h * HD + col], o[r]);
            }
        }
    }
}

// ---------------------------------------------------------------------------
// MFMA GEMM 2: out_v = attnv[16384][512] @ Wp + bias, scattered to vp_o/vf_o.
// grid (128, 4), block 256.
// ---------------------------------------------------------------------------
__global__ __launch_bounds__(256)
void gemm_proj_kernel(const _Float16* __restrict__ A, const _Float16* __restrict__ Bt,
                      const float* __restrict__ bp, float* __restrict__ out) {
    __shared__ __align__(16) _Float16 As[128 * 32];
    __shared__ __align__(16) _Float16 Bs[128 * 32];
    const int tid = threadIdx.x, lane = tid & 63, wave = tid >> 6;
    const int tm = blockIdx.x, tn = blockIdx.y;
    const int m_base = (wave >> 1) * 64, n_base = (wave & 1) * 64;
    const int quad = lane >> 4, l16 = lane & 15;

    f4 acc[4][4] = {};

    for (int k0 = 0; k0 < 512; k0 += 32) {
#pragma unroll
        for (int rnd = 0; rnd < 2; ++rnd) {
            int i = rnd * 256 + tid;
            int r = i >> 2, c = (i & 3) * 8;
            async16(A  + (size_t)(tm * 128 + r) * 512 + k0 + c, &As[i * 8]);
            async16(Bt + (size_t)(tn * 128 + r) * 512 + k0 + c, &Bs[i * 8]);
        }
        __syncthreads();

        h8 af[4], bf[4];
#pragma unroll
        for (int mi = 0; mi < 4; ++mi)
            af[mi] = *(const h8*)&As[(m_base + mi * 16 + l16) * 32 + quad * 8];
#pragma unroll
        for (int ni = 0; ni < 4; ++ni)
            bf[ni] = *(const h8*)&Bs[(n_base + ni * 16 + l16) * 32 + quad * 8];
#pragma unroll
        for (int mi = 0; mi < 4; ++mi)
#pragma unroll
            for (int ni = 0; ni < 4; ++ni)
                acc[mi][ni] = __builtin_amdgcn_mfma_f32_16x16x32_f16(
                    af[mi], bf[ni], acc[mi][ni], 0, 0, 0);
        __syncthreads();
    }

#pragma unroll
    for (int mi = 0; mi < 4; ++mi)
#pragma unroll
        for (int ni = 0; ni < 4; ++ni) {
            int row0 = tm * 128 + m_base + mi * 16 + quad * 4;
            int col  = tn * 128 + n_base + ni * 16 + l16;
            float bias = bp[col];
#pragma unroll
            for (int r = 0; r < 4; ++r) {
                int row = row0 + r;
                int bsq = row >> 4, t = row & 15;
                int b = bsq >> 8, s = bsq & 255;
                size_t off = (t < 8)
                    ? (VP_BASE + (size_t)((b * 8 + t) * SS + s) * DD + col)
                    : (VF_BASE + (size_t)((b * 8 + t - 8) * SS + s) * DD + col);
                out[off] = acc[mi][ni][r] + bias;
            }
        }
}

// ---------------------------------------------------------------------------
// mean-over-S (a_sum/256) + fp32 projection for the 64 a-rows.
// ---------------------------------------------------------------------------
__global__ __launch_bounds__(256)
void proj_a_kernel(const float* __restrict__ a_sum, const float* __restrict__ Wp,
                   const float* __restrict__ bp, float* __restrict__ out) {
    __shared__ float arow[DD];
    const int r = blockIdx.x;            // 0..63
    const int b = r >> 4, t = r & 15;
    const int tid = threadIdx.x;

    for (int i = tid; i < DD; i += 256)
        arow[i] = a_sum[(size_t)r * DD + i] * (1.0f / (float)SS);
    __syncthreads();

    for (int jj = 0; jj < 2; ++jj) {
        int j = jj * 256 + tid;
        float acc = bp[j];
        for (int k = 0; k < DD; ++k) acc += arow[k] * Wp[k * DD + j];
        size_t off = (t < 8) ? (AP_BASE + (size_t)(b * 8 + t) * DD + j)
                             : (AF_BASE + (size_t)(b * 8 + (t - 8)) * DD + j);
        out[off] = acc;
    }
}

// ---------------------------------------------------------------------------
extern "C" void kernel_launch(void* const* d_in, const int* in_sizes, int n_in,
                              void* d_out, int out_size, void* d_ws, size_t ws_size,
                              hipStream_t stream) {
    const float* v_p  = (const float*)d_in[0];
    const float* v_f  = (const float*)d_in[1];
    const float* a_p  = (const float*)d_in[2];
    const float* a_f  = (const float*)d_in[3];
    const float* Wqkv = (const float*)d_in[4];
    const float* Wp   = (const float*)d_in[5];
    const float* bp   = (const float*)d_in[6];
    float* out = (float*)d_out;

    // Workspace layout (~86.6 MB)
    char* w = (char*)d_ws;
    _Float16* tok   = (_Float16*)w;  w += (size_t)MPAD * DD * 2;    // 16.9 MB
    _Float16* qkv   = (_Float16*)w;  w += (size_t)MPAD * W3 * 2;    // 50.7 MB
    _Float16* attnv = (_Float16*)w;  w += (size_t)16384 * DD * 2;   // 16.8 MB
    _Float16* Wt    = (_Float16*)w;  w += (size_t)W3 * DD * 2;      //  1.6 MB
    _Float16* Wpt   = (_Float16*)w;  w += (size_t)DD * DD * 2;      //  0.5 MB
    float*    a_sum = (float*)w;     w += (size_t)64 * DD * 4;      //  0.13 MB

    hipMemsetAsync(a_sum, 0, 64 * DD * sizeof(float), stream);
    conv_tok_kernel<<<8224, 256, 0, stream>>>(v_p, v_f, a_p, a_f, tok);
    conv_w_kernel<<<4096, 256, 0, stream>>>(Wqkv, Wp, Wt, Wpt);
    gemm_qkv_kernel<<<dim3(129, 12), 256, 0, stream>>>(tok, Wt, qkv);
    attn3_kernel<<<1024, 256, 0, stream>>>(qkv, attnv, a_sum);
    gemm_proj_kernel<<<dim3(128, 4), 256, 0, stream>>>(attnv, Wpt, bp, out);
    proj_a_kernel<<<64, 256, 0, stream>>>(a_sum, Wp, bp, out);
}

// Round 4
// 241.224 us; speedup vs baseline: 5.7820x; 1.0710x over previous
//
#include <hip/hip_runtime.h>
#include <math.h>

// Problem constants (B=4, T_p=T_f=8, S=256, d=512, heads=8)
#define BB   4
#define SS   256
#define DD   512
#define HH   8
#define HD   64
#define HALF 32
#define TT   32      // total tokens per sequence
#define TV   16      // vp+vf tokens (vary per (b,s))
#define W3   1536    // 3*d
#define MROWS  16448 // 16384 v-rows + 64 unique a-rows
#define MPAD   16512 // 129 * 128

#define VP_BASE 0
#define VF_BASE 4194304      // 4*8*256*512
#define AP_BASE 8388608      // 2*4194304
#define AF_BASE 8404992      // AP_BASE + 4*8*512

#define LN10000_OVER_HALF (9.210340371976184f / 32.0f)

typedef _Float16 h2 __attribute__((ext_vector_type(2)));
typedef _Float16 h4 __attribute__((ext_vector_type(4)));
typedef _Float16 h8 __attribute__((ext_vector_type(8)));
typedef float    f4 __attribute__((ext_vector_type(4)));
typedef float    f16v __attribute__((ext_vector_type(16)));

__device__ __forceinline__ float ropefreq(int i) {
    return __expf(-(float)i * LN10000_OVER_HALF);   // 10000^(-i/32)
}

// async global->LDS, 16 bytes per lane (global_load_lds_dwordx4)
typedef __attribute__((address_space(3))) void*       lds_ptr_t;
typedef const __attribute__((address_space(1))) void* gbl_ptr_t;
__device__ __forceinline__ void async16(const void* g, void* l) {
    __builtin_amdgcn_global_load_lds((gbl_ptr_t)g, (lds_ptr_t)l, 16, 0, 0);
}

// ---------------------------------------------------------------------------
// Fused prep kernel.
// Blocks [0, 8224): gather tokens into fp16 tok[16512][512]
//   rows 0..16383: v-tokens (bs=r/16, t=r%16); rows 16384..16447: a-tokens.
// Blocks [8224, 8480): 64x64 LDS-tile transpose+convert of Wqkv -> Wt and
//   Wp -> Wpt (K-major for MFMA B-frag loads), both sides coalesced.
// ---------------------------------------------------------------------------
__global__ __launch_bounds__(256)
void conv_kernel(const float* __restrict__ v_p, const float* __restrict__ v_f,
                 const float* __restrict__ a_p, const float* __restrict__ a_f,
                 const float* __restrict__ Wqkv, const float* __restrict__ Wp,
                 _Float16* __restrict__ tok, _Float16* __restrict__ Wt,
                 _Float16* __restrict__ Wpt) {
    __shared__ float tile[64 * 65];
    const int bid = blockIdx.x, tid = threadIdx.x;
    if (bid < 8224) {
        int id = bid * 256 + tid;
        int e  = id * 4;
        int r  = e >> 9, c = e & 511;
        const float* src;
        if (r < 16384) {
            int bs = r >> 4, t = r & 15, b = bs >> 8, s = bs & 255;
            src = (t < 8) ? v_p + (size_t)((b * 8 + t) * SS + s) * DD
                          : v_f + (size_t)((b * 8 + t - 8) * SS + s) * DD;
        } else {
            int idx = r - 16384, b = idx >> 4, t2 = idx & 15;
            src = (t2 < 8) ? a_p + (size_t)(b * 8 + t2) * DD
                           : a_f + (size_t)(b * 8 + (t2 - 8)) * DD;
        }
        float4 v = *(const float4*)(src + c);
        h4 o = { (_Float16)v.x, (_Float16)v.y, (_Float16)v.z, (_Float16)v.w };
        *(h4*)(tok + (size_t)r * DD + c) = o;
    } else {
        int tb = bid - 8224;                 // 0..255
        const float* src; _Float16* dst; int ld, k0, n0;
        if (tb < 192) {                      // Wqkv: 512(k) x 1536(n), 8x24 tiles
            src = Wqkv; dst = Wt; ld = W3;
            k0 = (tb & 7) * 64; n0 = (tb >> 3) * 64;
        } else {                             // Wp: 512 x 512, 8x8 tiles
            int t2 = tb - 192;
            src = Wp; dst = Wpt; ld = DD;
            k0 = (t2 & 7) * 64; n0 = (t2 >> 3) * 64;
        }
#pragma unroll
        for (int p = 0; p < 16; ++p) {
            int idx = p * 256 + tid, rr = idx >> 6, cc = idx & 63;
            tile[rr * 65 + cc] = src[(size_t)(k0 + rr) * ld + n0 + cc];
        }
        __syncthreads();
#pragma unroll
        for (int p = 0; p < 16; ++p) {
            int idx = p * 256 + tid, rr = idx >> 6, cc = idx & 63;
            dst[(size_t)(n0 + rr) * DD + k0 + cc] = (_Float16)tile[cc * 65 + rr];
        }
    }
}

// ---------------------------------------------------------------------------
// MFMA GEMM 1: qkv[16512][1536] = tok[16512][512] @ Wqkv (fp16 in/out)
// grid (129, 12), block 256.
// ---------------------------------------------------------------------------
__global__ __launch_bounds__(256)
void gemm_qkv_kernel(const _Float16* __restrict__ A, const _Float16* __restrict__ Bt,
                     _Float16* __restrict__ C) {
    __shared__ __align__(16) _Float16 As[128 * 32];
    __shared__ __align__(16) _Float16 Bs[128 * 32];
    const int tid = threadIdx.x, lane = tid & 63, wave = tid >> 6;
    const int tm = blockIdx.x, tn = blockIdx.y;
    const int m_base = (wave >> 1) * 64, n_base = (wave & 1) * 64;
    const int quad = lane >> 4, l16 = lane & 15;

    f4 acc[4][4] = {};

    for (int k0 = 0; k0 < 512; k0 += 32) {
#pragma unroll
        for (int rnd = 0; rnd < 2; ++rnd) {
            int i = rnd * 256 + tid;
            int r = i >> 2, c = (i & 3) * 8;
            async16(A  + (size_t)(tm * 128 + r) * 512 + k0 + c, &As[i * 8]);
            async16(Bt + (size_t)(tn * 128 + r) * 512 + k0 + c, &Bs[i * 8]);
        }
        __syncthreads();

        h8 af[4], bf[4];
#pragma unroll
        for (int mi = 0; mi < 4; ++mi)
            af[mi] = *(const h8*)&As[(m_base + mi * 16 + l16) * 32 + quad * 8];
#pragma unroll
        for (int ni = 0; ni < 4; ++ni)
            bf[ni] = *(const h8*)&Bs[(n_base + ni * 16 + l16) * 32 + quad * 8];
#pragma unroll
        for (int mi = 0; mi < 4; ++mi)
#pragma unroll
            for (int ni = 0; ni < 4; ++ni)
                acc[mi][ni] = __builtin_amdgcn_mfma_f32_16x16x32_f16(
                    af[mi], bf[ni], acc[mi][ni], 0, 0, 0);
        __syncthreads();
    }

#pragma unroll
    for (int mi = 0; mi < 4; ++mi)
#pragma unroll
        for (int ni = 0; ni < 4; ++ni) {
            int row = tm * 128 + m_base + mi * 16 + quad * 4;
            int col = tn * 128 + n_base + ni * 16 + l16;
#pragma unroll
            for (int r = 0; r < 4; ++r)
                C[(size_t)(row + r) * W3 + col] = (_Float16)acc[mi][ni][r];
        }
}

// ---------------------------------------------------------------------------
// MFMA attention: one block per (b,s), 4 waves, wave w handles heads w, w+4.
// Wave-private LDS; no __syncthreads. RoPE in registers (pos = row = lane&31).
// QK^T and PV via v_mfma_f32_32x32x16_f16. Outputs staged in LDS, then
// written as coalesced 16 B chunks: v-rows -> attnv, a-rows -> attna (dense,
// no atomics; mean-over-S folded into proj_a).
// ---------------------------------------------------------------------------
__global__ __launch_bounds__(256)
void attn4_kernel(const _Float16* __restrict__ qkv, _Float16* __restrict__ attnv,
                  _Float16* __restrict__ attna) {
    __shared__ _Float16 VlA[4][32 * 72];   // per-wave V tile, stride 72
    __shared__ _Float16 PlA[4][32 * 40];   // per-wave P tile, stride 40
    __shared__ _Float16 OlA[4][32 * 72];   // per-wave O tile, stride 72
    const int bs = blockIdx.x, b = bs >> 8;
    const int tid = threadIdx.x, wave = tid >> 6, lane = tid & 63;
    const int t = lane & 31, half = lane >> 5;
    _Float16* vl = &VlA[wave][0];
    _Float16* pl = &PlA[wave][0];
    _Float16* ol = &OlA[wave][0];

    // this lane's token row in the qkv matrix (a-rows are deduped at 16384+)
    const size_t row = (t < 16) ? (size_t)(bs * 16 + t)
                                : (size_t)(16384 + b * 16 + (t - 16));
    const _Float16* rowp = qkv + row * W3;

    // RoPE cos/sin for this lane (pos = t, freq index = 8*half+j and 16+8*half+j)
    float ccA[8], ssA[8], ccB[8], ssB[8];
#pragma unroll
    for (int j = 0; j < 8; ++j) {
        float aA = (float)t * ropefreq(8 * half + j);
        float aB = (float)t * ropefreq(16 + 8 * half + j);
        __sincosf(aA, &ssA[j], &ccA[j]);
        __sincosf(aB, &ssB[j], &ccB[j]);
    }

    for (int hh = 0; hh < 2; ++hh) {
        const int h = wave + 4 * hh;
        const _Float16* qp = rowp + h * HD;

        // ---- stage V (cols 32*half..+31 of this lane's row) ----
        h8 v0 = *(const h8*)(qp + 2 * DD + 32 * half);
        h8 v1 = *(const h8*)(qp + 2 * DD + 32 * half + 8);
        h8 v2 = *(const h8*)(qp + 2 * DD + 32 * half + 16);
        h8 v3 = *(const h8*)(qp + 2 * DD + 32 * half + 24);
        *(h8*)&vl[t * 72 + 32 * half +  0] = v0;
        *(h8*)&vl[t * 72 + 32 * half +  8] = v1;
        *(h8*)&vl[t * 72 + 32 * half + 16] = v2;
        *(h8*)&vl[t * 72 + 32 * half + 24] = v3;

        // ---- load Q,K chunks (chunk c covers cols 8c..8c+7; lane owns
        //      chunks half, half+2, half+4, half+6; RoPE pairs (c, c+4)) ----
        h8 q0 = *(const h8*)(qp + 8 * half);
        h8 q1 = *(const h8*)(qp + 8 * half + 16);
        h8 q2 = *(const h8*)(qp + 8 * half + 32);
        h8 q3 = *(const h8*)(qp + 8 * half + 48);
        h8 k0 = *(const h8*)(qp + DD + 8 * half);
        h8 k1 = *(const h8*)(qp + DD + 8 * half + 16);
        h8 k2 = *(const h8*)(qp + DD + 8 * half + 32);
        h8 k3 = *(const h8*)(qp + DD + 8 * half + 48);

        h8 qf0, qf1, qf2, qf3, kf0, kf1, kf2, kf3;
#pragma unroll
        for (int j = 0; j < 8; ++j) {
            // Q: fold in softmax scale 1/8
            float x1 = (float)q0[j], x2 = (float)q2[j];
            qf0[j] = (_Float16)(0.125f * (x1 * ccA[j] - x2 * ssA[j]));
            qf2[j] = (_Float16)(0.125f * (x2 * ccA[j] + x1 * ssA[j]));
            x1 = (float)q1[j]; x2 = (float)q3[j];
            qf1[j] = (_Float16)(0.125f * (x1 * ccB[j] - x2 * ssB[j]));
            qf3[j] = (_Float16)(0.125f * (x2 * ccB[j] + x1 * ssB[j]));
            // K: no scale
            x1 = (float)k0[j]; x2 = (float)k2[j];
            kf0[j] = (_Float16)(x1 * ccA[j] - x2 * ssA[j]);
            kf2[j] = (_Float16)(x2 * ccA[j] + x1 * ssA[j]);
            x1 = (float)k1[j]; x2 = (float)k3[j];
            kf1[j] = (_Float16)(x1 * ccB[j] - x2 * ssB[j]);
            kf3[j] = (_Float16)(x2 * ccB[j] + x1 * ssB[j]);
        }

        // ---- scores S = (Q/8) K^T : 4 MFMAs over K=64 ----
        f16v s = {};
        s = __builtin_amdgcn_mfma_f32_32x32x16_f16(qf0, kf0, s, 0, 0, 0);
        s = __builtin_amdgcn_mfma_f32_32x32x16_f16(qf1, kf1, s, 0, 0, 0);
        s = __builtin_amdgcn_mfma_f32_32x32x16_f16(qf2, kf2, s, 0, 0, 0);
        s = __builtin_amdgcn_mfma_f32_32x32x16_f16(qf3, kf3, s, 0, 0, 0);

        // ---- softmax per row (row lives in this lane's 32-lane half) ----
#pragma unroll
        for (int r = 0; r < 16; ++r) {
            float m = s[r];
#pragma unroll
            for (int mask = 1; mask <= 16; mask <<= 1)
                m = fmaxf(m, __shfl_xor(m, mask));
            float e = __expf(s[r] - m);
            float sm = e;
#pragma unroll
            for (int mask = 1; mask <= 16; mask <<= 1)
                sm += __shfl_xor(sm, mask);
            float p = e / sm;
            int rr = (r & 3) + 8 * (r >> 2) + 4 * half;
            pl[rr * 40 + t] = (_Float16)p;
        }

        // ---- O = P V : 2 n-halves x 2 k-steps; stage into LDS O tile ----
#pragma unroll
        for (int n0 = 0; n0 < 2; ++n0) {
            f16v o = {};
#pragma unroll
            for (int kk = 0; kk < 2; ++kk) {
                h8 pf = *(const h8*)&pl[t * 40 + kk * 16 + half * 8];
                h8 vf;
#pragma unroll
                for (int jj = 0; jj < 8; ++jj)
                    vf[jj] = vl[(kk * 16 + half * 8 + jj) * 72 + n0 * 32 + t];
                o = __builtin_amdgcn_mfma_f32_32x32x16_f16(pf, vf, o, 0, 0, 0);
            }
#pragma unroll
            for (int r = 0; r < 16; ++r) {
                int i = (r & 3) + 8 * (r >> 2) + 4 * half;
                ol[i * 72 + n0 * 32 + t] = (_Float16)o[r];
            }
        }

        // ---- coalesced write-back: 16 B per lane, 128 B per 8 lanes ----
#pragma unroll
        for (int rr = 0; rr < 4; ++rr) {
            int i = rr * 8 + (lane >> 3);
            int c = (lane & 7) * 8;
            h8 val = *(const h8*)&ol[i * 72 + c];
            if (rr < 2)   // i < 16: v-rows
                *(h8*)&attnv[(size_t)(bs * 16 + i) * DD + h * HD + c] = val;
            else          // a-rows
                *(h8*)&attna[((size_t)bs * 16 + (i - 16)) * DD + h * HD + c] = val;
        }
    }
}

// ---------------------------------------------------------------------------
// MFMA GEMM 2: out_v = attnv[16384][512] @ Wp + bias, scattered to vp_o/vf_o.
// grid (128, 4), block 256.
// ---------------------------------------------------------------------------
__global__ __launch_bounds__(256)
void gemm_proj_kernel(const _Float16* __restrict__ A, const _Float16* __restrict__ Bt,
                      const float* __restrict__ bp, float* __restrict__ out) {
    __shared__ __align__(16) _Float16 As[128 * 32];
    __shared__ __align__(16) _Float16 Bs[128 * 32];
    const int tid = threadIdx.x, lane = tid & 63, wave = tid >> 6;
    const int tm = blockIdx.x, tn = blockIdx.y;
    const int m_base = (wave >> 1) * 64, n_base = (wave & 1) * 64;
    const int quad = lane >> 4, l16 = lane & 15;

    f4 acc[4][4] = {};

    for (int k0 = 0; k0 < 512; k0 += 32) {
#pragma unroll
        for (int rnd = 0; rnd < 2; ++rnd) {
            int i = rnd * 256 + tid;
            int r = i >> 2, c = (i & 3) * 8;
            async16(A  + (size_t)(tm * 128 + r) * 512 + k0 + c, &As[i * 8]);
            async16(Bt + (size_t)(tn * 128 + r) * 512 + k0 + c, &Bs[i * 8]);
        }
        __syncthreads();

        h8 af[4], bf[4];
#pragma unroll
        for (int mi = 0; mi < 4; ++mi)
            af[mi] = *(const h8*)&As[(m_base + mi * 16 + l16) * 32 + quad * 8];
#pragma unroll
        for (int ni = 0; ni < 4; ++ni)
            bf[ni] = *(const h8*)&Bs[(n_base + ni * 16 + l16) * 32 + quad * 8];
#pragma unroll
        for (int mi = 0; mi < 4; ++mi)
#pragma unroll
            for (int ni = 0; ni < 4; ++ni)
                acc[mi][ni] = __builtin_amdgcn_mfma_f32_16x16x32_f16(
                    af[mi], bf[ni], acc[mi][ni], 0, 0, 0);
        __syncthreads();
    }

#pragma unroll
    for (int mi = 0; mi < 4; ++mi)
#pragma unroll
        for (int ni = 0; ni < 4; ++ni) {
            int row0 = tm * 128 + m_base + mi * 16 + quad * 4;
            int col  = tn * 128 + n_base + ni * 16 + l16;
            float bias = bp[col];
#pragma unroll
            for (int r = 0; r < 4; ++r) {
                int row = row0 + r;
                int bsq = row >> 4, t = row & 15;
                int b = bsq >> 8, s = bsq & 255;
                size_t off = (t < 8)
                    ? (VP_BASE + (size_t)((b * 8 + t) * SS + s) * DD + col)
                    : (VF_BASE + (size_t)((b * 8 + t - 8) * SS + s) * DD + col);
                out[off] = acc[mi][ni][r] + bias;
            }
        }
}

// ---------------------------------------------------------------------------
// a-rows: mean over S (reads dense attna) + fp32 projection, 64 blocks.
// ---------------------------------------------------------------------------
__global__ __launch_bounds__(256)
void proj_a_kernel(const _Float16* __restrict__ attna, const float* __restrict__ Wp,
                   const float* __restrict__ bp, float* __restrict__ out) {
    __shared__ float arow[DD];
    const int r = blockIdx.x;            // 0..63
    const int b = r >> 4, t = r & 15;
    const int tid = threadIdx.x;

    float acc0 = 0.f, acc1 = 0.f;
    for (int s = 0; s < SS; ++s) {
        h2 v = *(const h2*)&attna[((size_t)((b * SS + s) * 16 + t)) * DD + tid * 2];
        acc0 += (float)v.x;
        acc1 += (float)v.y;
    }
    arow[tid * 2]     = acc0 * (1.0f / (float)SS);
    arow[tid * 2 + 1] = acc1 * (1.0f / (float)SS);
    __syncthreads();

    for (int jj = 0; jj < 2; ++jj) {
        int j = jj * 256 + tid;
        float acc = bp[j];
        for (int k = 0; k < DD; ++k) acc += arow[k] * Wp[k * DD + j];
        size_t off = (t < 8) ? (AP_BASE + (size_t)(b * 8 + t) * DD + j)
                             : (AF_BASE + (size_t)(b * 8 + (t - 8)) * DD + j);
        out[off] = acc;
    }
}

// ---------------------------------------------------------------------------
extern "C" void kernel_launch(void* const* d_in, const int* in_sizes, int n_in,
                              void* d_out, int out_size, void* d_ws, size_t ws_size,
                              hipStream_t stream) {
    const float* v_p  = (const float*)d_in[0];
    const float* v_f  = (const float*)d_in[1];
    const float* a_p  = (const float*)d_in[2];
    const float* a_f  = (const float*)d_in[3];
    const float* Wqkv = (const float*)d_in[4];
    const float* Wp   = (const float*)d_in[5];
    const float* bp   = (const float*)d_in[6];
    float* out = (float*)d_out;

    // Workspace layout (~86.6 MB). attna ALIASES tok: tok is dead after
    // gemm_qkv_kernel, attna is written only in attn4_kernel (later on stream).
    char* w = (char*)d_ws;
    _Float16* tok   = (_Float16*)w;  w += (size_t)MPAD * DD * 2;    // 16.9 MB
    _Float16* qkv   = (_Float16*)w;  w += (size_t)MPAD * W3 * 2;    // 50.7 MB
    _Float16* attnv = (_Float16*)w;  w += (size_t)16384 * DD * 2;   // 16.8 MB
    _Float16* Wt    = (_Float16*)w;  w += (size_t)W3 * DD * 2;      //  1.6 MB
    _Float16* Wpt   = (_Float16*)w;  w += (size_t)DD * DD * 2;      //  0.5 MB
    _Float16* attna = tok;                                          // alias

    conv_kernel<<<8480, 256, 0, stream>>>(v_p, v_f, a_p, a_f, Wqkv, Wp,
                                          tok, Wt, Wpt);
    gemm_qkv_kernel<<<dim3(129, 12), 256, 0, stream>>>(tok, Wt, qkv);
    attn4_kernel<<<1024, 256, 0, stream>>>(qkv, attnv, attna);
    gemm_proj_kernel<<<dim3(128, 4), 256, 0, stream>>>(attnv, Wpt, bp, out);
    proj_a_kernel<<<64, 256, 0, stream>>>(attna, Wp, bp, out);
}

// Round 5
// 222.734 us; speedup vs baseline: 6.2619x; 1.0830x over previous
//
#include <hip/hip_runtime.h>
#include <math.h>

// Problem constants (B=4, T_p=T_f=8, S=256, d=512, heads=8)
#define BB   4
#define SS   256
#define DD   512
#define HH   8
#define HD   64
#define HALF 32
#define TT   32      // total tokens per sequence
#define TV   16      // vp+vf tokens (vary per (b,s))
#define W3   1536    // 3*d
#define MROWS  16448 // 16384 v-rows + 64 unique a-rows
#define MPAD   16512 // 129 * 128

#define VP_BASE 0
#define VF_BASE 4194304      // 4*8*256*512
#define AP_BASE 8388608      // 2*4194304
#define AF_BASE 8404992      // AP_BASE + 4*8*512

#define LN10000_OVER_HALF (9.210340371976184f / 32.0f)

typedef _Float16 h2 __attribute__((ext_vector_type(2)));
typedef _Float16 h4 __attribute__((ext_vector_type(4)));
typedef _Float16 h8 __attribute__((ext_vector_type(8)));
typedef float    f4 __attribute__((ext_vector_type(4)));
typedef float    f16v __attribute__((ext_vector_type(16)));

__device__ __forceinline__ float ropefreq(int i) {
    return __expf(-(float)i * LN10000_OVER_HALF);   // 10000^(-i/32)
}

// async global->LDS, 16 bytes per lane (global_load_lds_dwordx4)
typedef __attribute__((address_space(3))) void*       lds_ptr_t;
typedef const __attribute__((address_space(1))) void* gbl_ptr_t;
__device__ __forceinline__ void async16(const void* g, void* l) {
    __builtin_amdgcn_global_load_lds((gbl_ptr_t)g, (lds_ptr_t)l, 16, 0, 0);
}

// ---------------------------------------------------------------------------
// Fused prep kernel.
// Blocks [0, 8224): gather tokens into fp16 tok[16512][512]
//   rows 0..16383: v-tokens (bs=r/16, t=r%16); rows 16384..16447: a-tokens.
// Blocks [8224, 8480): 64x64 LDS-tile transpose+convert of Wqkv -> Wt and
//   Wp -> Wpt (K-major for MFMA B-frag loads), both sides coalesced.
// ---------------------------------------------------------------------------
__global__ __launch_bounds__(256)
void conv_kernel(const float* __restrict__ v_p, const float* __restrict__ v_f,
                 const float* __restrict__ a_p, const float* __restrict__ a_f,
                 const float* __restrict__ Wqkv, const float* __restrict__ Wp,
                 _Float16* __restrict__ tok, _Float16* __restrict__ Wt,
                 _Float16* __restrict__ Wpt) {
    __shared__ float tile[64 * 65];
    const int bid = blockIdx.x, tid = threadIdx.x;
    if (bid < 8224) {
        int id = bid * 256 + tid;
        int e  = id * 4;
        int r  = e >> 9, c = e & 511;
        const float* src;
        if (r < 16384) {
            int bs = r >> 4, t = r & 15, b = bs >> 8, s = bs & 255;
            src = (t < 8) ? v_p + (size_t)((b * 8 + t) * SS + s) * DD
                          : v_f + (size_t)((b * 8 + t - 8) * SS + s) * DD;
        } else {
            int idx = r - 16384, b = idx >> 4, t2 = idx & 15;
            src = (t2 < 8) ? a_p + (size_t)(b * 8 + t2) * DD
                           : a_f + (size_t)(b * 8 + (t2 - 8)) * DD;
        }
        float4 v = *(const float4*)(src + c);
        h4 o = { (_Float16)v.x, (_Float16)v.y, (_Float16)v.z, (_Float16)v.w };
        *(h4*)(tok + (size_t)r * DD + c) = o;
    } else {
        int tb = bid - 8224;                 // 0..255
        const float* src; _Float16* dst; int ld, k0, n0;
        if (tb < 192) {                      // Wqkv: 512(k) x 1536(n), 8x24 tiles
            src = Wqkv; dst = Wt; ld = W3;
            k0 = (tb & 7) * 64; n0 = (tb >> 3) * 64;
        } else {                             // Wp: 512 x 512, 8x8 tiles
            int t2 = tb - 192;
            src = Wp; dst = Wpt; ld = DD;
            k0 = (t2 & 7) * 64; n0 = (t2 >> 3) * 64;
        }
#pragma unroll
        for (int p = 0; p < 16; ++p) {
            int idx = p * 256 + tid, rr = idx >> 6, cc = idx & 63;
            tile[rr * 65 + cc] = src[(size_t)(k0 + rr) * ld + n0 + cc];
        }
        __syncthreads();
#pragma unroll
        for (int p = 0; p < 16; ++p) {
            int idx = p * 256 + tid, rr = idx >> 6, cc = idx & 63;
            dst[(size_t)(n0 + rr) * DD + k0 + cc] = (_Float16)tile[cc * 65 + rr];
        }
    }
}

// ---------------------------------------------------------------------------
// MFMA GEMM 1: qkv[16512][1536] = tok[16512][512] @ Wqkv (fp16 in/out)
// 128x256 tiles; 1-D grid of 129*6 blocks, tn-fastest (consecutive blocks
// share the A-tile for L2/L3 reuse). acc 4x8 per wave.
// ---------------------------------------------------------------------------
__global__ __launch_bounds__(256, 2)
void gemm_qkv_kernel(const _Float16* __restrict__ A, const _Float16* __restrict__ Bt,
                     _Float16* __restrict__ C) {
    __shared__ __align__(16) _Float16 As[128 * 32];   //  8 KB
    __shared__ __align__(16) _Float16 Bs[256 * 32];   // 16 KB
    const int tid = threadIdx.x, lane = tid & 63, wave = tid >> 6;
    const int bid = blockIdx.x;
    const int tm = bid / 6, tn = bid % 6;
    const int m_base = (wave >> 1) * 64, n_base = (wave & 1) * 128;
    const int quad = lane >> 4, l16 = lane & 15;

    f4 acc[4][8] = {};

    for (int k0 = 0; k0 < 512; k0 += 32) {
#pragma unroll
        for (int rnd = 0; rnd < 2; ++rnd) {          // A: 128 rows x 32
            int i = rnd * 256 + tid;                 // [0,512)
            int r = i >> 2, c = (i & 3) * 8;
            async16(A + (size_t)(tm * 128 + r) * 512 + k0 + c, &As[i * 8]);
        }
#pragma unroll
        for (int rnd = 0; rnd < 4; ++rnd) {          // B: 256 rows x 32
            int i = rnd * 256 + tid;                 // [0,1024)
            int r = i >> 2, c = (i & 3) * 8;
            async16(Bt + (size_t)(tn * 256 + r) * 512 + k0 + c, &Bs[i * 8]);
        }
        __syncthreads();

        h8 af[4], bf[8];
#pragma unroll
        for (int mi = 0; mi < 4; ++mi)
            af[mi] = *(const h8*)&As[(m_base + mi * 16 + l16) * 32 + quad * 8];
#pragma unroll
        for (int ni = 0; ni < 8; ++ni)
            bf[ni] = *(const h8*)&Bs[(n_base + ni * 16 + l16) * 32 + quad * 8];
#pragma unroll
        for (int mi = 0; mi < 4; ++mi)
#pragma unroll
            for (int ni = 0; ni < 8; ++ni)
                acc[mi][ni] = __builtin_amdgcn_mfma_f32_16x16x32_f16(
                    af[mi], bf[ni], acc[mi][ni], 0, 0, 0);
        __syncthreads();
    }

#pragma unroll
    for (int mi = 0; mi < 4; ++mi)
#pragma unroll
        for (int ni = 0; ni < 8; ++ni) {
            int row = tm * 128 + m_base + mi * 16 + quad * 4;
            int col = tn * 256 + n_base + ni * 16 + l16;
#pragma unroll
            for (int r = 0; r < 4; ++r)
                C[(size_t)(row + r) * W3 + col] = (_Float16)acc[mi][ni][r];
        }
}

// ---------------------------------------------------------------------------
// MFMA attention: grid 2048 = (b,s) x head-group; 4 waves, wave w handles
// head w + 4*hh. Wave-private LDS; no __syncthreads. RoPE in registers
// (pos = row = lane&31). QK^T and PV via v_mfma_f32_32x32x16_f16.
// O held in registers through PV, then staged into the (dead) V tile for
// coalesced 16 B write-back. v-rows -> attnv, a-rows -> attna (dense).
// ---------------------------------------------------------------------------
__global__ __launch_bounds__(256)
void attn5_kernel(const _Float16* __restrict__ qkv, _Float16* __restrict__ attnv,
                  _Float16* __restrict__ attna) {
    __shared__ _Float16 VlA[4][32 * 72];   // per-wave V tile (reused for O)
    __shared__ _Float16 PlA[4][32 * 40];   // per-wave P tile
    const int bid = blockIdx.x;
    const int bs = bid >> 1, hh = bid & 1, b = bs >> 8;
    const int tid = threadIdx.x, wave = tid >> 6, lane = tid & 63;
    const int t = lane & 31, half = lane >> 5;
    _Float16* vl = &VlA[wave][0];
    _Float16* pl = &PlA[wave][0];
    const int h = wave + 4 * hh;

    // this lane's token row in the qkv matrix (a-rows are deduped at 16384+)
    const size_t row = (t < 16) ? (size_t)(bs * 16 + t)
                                : (size_t)(16384 + b * 16 + (t - 16));
    const _Float16* qp = qkv + row * W3 + h * HD;

    // RoPE cos/sin for this lane (pos = t, freq index = 8*half+j and 16+8*half+j)
    float ccA[8], ssA[8], ccB[8], ssB[8];
#pragma unroll
    for (int j = 0; j < 8; ++j) {
        float aA = (float)t * ropefreq(8 * half + j);
        float aB = (float)t * ropefreq(16 + 8 * half + j);
        __sincosf(aA, &ssA[j], &ccA[j]);
        __sincosf(aB, &ssB[j], &ccB[j]);
    }

    // ---- stage V (cols 32*half..+31 of this lane's row) ----
    h8 v0 = *(const h8*)(qp + 2 * DD + 32 * half);
    h8 v1 = *(const h8*)(qp + 2 * DD + 32 * half + 8);
    h8 v2 = *(const h8*)(qp + 2 * DD + 32 * half + 16);
    h8 v3 = *(const h8*)(qp + 2 * DD + 32 * half + 24);
    *(h8*)&vl[t * 72 + 32 * half +  0] = v0;
    *(h8*)&vl[t * 72 + 32 * half +  8] = v1;
    *(h8*)&vl[t * 72 + 32 * half + 16] = v2;
    *(h8*)&vl[t * 72 + 32 * half + 24] = v3;

    // ---- load Q,K chunks (chunk c covers cols 8c..8c+7; lane owns
    //      chunks half, half+2, half+4, half+6; RoPE pairs (c, c+4)) ----
    h8 q0 = *(const h8*)(qp + 8 * half);
    h8 q1 = *(const h8*)(qp + 8 * half + 16);
    h8 q2 = *(const h8*)(qp + 8 * half + 32);
    h8 q3 = *(const h8*)(qp + 8 * half + 48);
    h8 k0 = *(const h8*)(qp + DD + 8 * half);
    h8 k1 = *(const h8*)(qp + DD + 8 * half + 16);
    h8 k2 = *(const h8*)(qp + DD + 8 * half + 32);
    h8 k3 = *(const h8*)(qp + DD + 8 * half + 48);

    h8 qf0, qf1, qf2, qf3, kf0, kf1, kf2, kf3;
#pragma unroll
    for (int j = 0; j < 8; ++j) {
        // Q: fold in softmax scale 1/8
        float x1 = (float)q0[j], x2 = (float)q2[j];
        qf0[j] = (_Float16)(0.125f * (x1 * ccA[j] - x2 * ssA[j]));
        qf2[j] = (_Float16)(0.125f * (x2 * ccA[j] + x1 * ssA[j]));
        x1 = (float)q1[j]; x2 = (float)q3[j];
        qf1[j] = (_Float16)(0.125f * (x1 * ccB[j] - x2 * ssB[j]));
        qf3[j] = (_Float16)(0.125f * (x2 * ccB[j] + x1 * ssB[j]));
        // K: no scale
        x1 = (float)k0[j]; x2 = (float)k2[j];
        kf0[j] = (_Float16)(x1 * ccA[j] - x2 * ssA[j]);
        kf2[j] = (_Float16)(x2 * ccA[j] + x1 * ssA[j]);
        x1 = (float)k1[j]; x2 = (float)k3[j];
        kf1[j] = (_Float16)(x1 * ccB[j] - x2 * ssB[j]);
        kf3[j] = (_Float16)(x2 * ccB[j] + x1 * ssB[j]);
    }

    // ---- scores S = (Q/8) K^T : 4 MFMAs over K=64 ----
    f16v s = {};
    s = __builtin_amdgcn_mfma_f32_32x32x16_f16(qf0, kf0, s, 0, 0, 0);
    s = __builtin_amdgcn_mfma_f32_32x32x16_f16(qf1, kf1, s, 0, 0, 0);
    s = __builtin_amdgcn_mfma_f32_32x32x16_f16(qf2, kf2, s, 0, 0, 0);
    s = __builtin_amdgcn_mfma_f32_32x32x16_f16(qf3, kf3, s, 0, 0, 0);

    // ---- softmax per row (row lives in this lane's 32-lane half) ----
#pragma unroll
    for (int r = 0; r < 16; ++r) {
        float m = s[r];
#pragma unroll
        for (int mask = 1; mask <= 16; mask <<= 1)
            m = fmaxf(m, __shfl_xor(m, mask));
        float e = __expf(s[r] - m);
        float sm = e;
#pragma unroll
        for (int mask = 1; mask <= 16; mask <<= 1)
            sm += __shfl_xor(sm, mask);
        float p = e / sm;
        int rr = (r & 3) + 8 * (r >> 2) + 4 * half;
        pl[rr * 40 + t] = (_Float16)p;
    }

    // ---- O = P V : 2 n-halves x 2 k-steps; O kept in registers ----
    f16v o_acc[2];
#pragma unroll
    for (int n0 = 0; n0 < 2; ++n0) {
        f16v o = {};
#pragma unroll
        for (int kk = 0; kk < 2; ++kk) {
            h8 pf = *(const h8*)&pl[t * 40 + kk * 16 + half * 8];
            h8 vf;
#pragma unroll
            for (int jj = 0; jj < 8; ++jj)
                vf[jj] = vl[(kk * 16 + half * 8 + jj) * 72 + n0 * 32 + t];
            o = __builtin_amdgcn_mfma_f32_32x32x16_f16(pf, vf, o, 0, 0, 0);
        }
        o_acc[n0] = o;
    }

    // ---- V tile is dead; stage O into it (wave-synchronous) ----
#pragma unroll
    for (int n0 = 0; n0 < 2; ++n0)
#pragma unroll
        for (int r = 0; r < 16; ++r) {
            int i = (r & 3) + 8 * (r >> 2) + 4 * half;
            vl[i * 72 + n0 * 32 + t] = (_Float16)o_acc[n0][r];
        }

    // ---- coalesced write-back: 16 B per lane, 128 B per 8 lanes ----
#pragma unroll
    for (int rr = 0; rr < 4; ++rr) {
        int i = rr * 8 + (lane >> 3);
        int c = (lane & 7) * 8;
        h8 val = *(const h8*)&vl[i * 72 + c];
        if (rr < 2)   // i < 16: v-rows
            *(h8*)&attnv[(size_t)(bs * 16 + i) * DD + h * HD + c] = val;
        else          // a-rows
            *(h8*)&attna[((size_t)bs * 16 + (i - 16)) * DD + h * HD + c] = val;
    }
}

// ---------------------------------------------------------------------------
// MFMA GEMM 2: out_v = attnv[16384][512] @ Wp + bias, scattered to vp_o/vf_o.
// 1-D grid 512, tn-fastest (A-tile reuse).
// ---------------------------------------------------------------------------
__global__ __launch_bounds__(256)
void gemm_proj_kernel(const _Float16* __restrict__ A, const _Float16* __restrict__ Bt,
                      const float* __restrict__ bp, float* __restrict__ out) {
    __shared__ __align__(16) _Float16 As[128 * 32];
    __shared__ __align__(16) _Float16 Bs[128 * 32];
    const int tid = threadIdx.x, lane = tid & 63, wave = tid >> 6;
    const int bid = blockIdx.x;
    const int tm = bid >> 2, tn = bid & 3;
    const int m_base = (wave >> 1) * 64, n_base = (wave & 1) * 64;
    const int quad = lane >> 4, l16 = lane & 15;

    f4 acc[4][4] = {};

    for (int k0 = 0; k0 < 512; k0 += 32) {
#pragma unroll
        for (int rnd = 0; rnd < 2; ++rnd) {
            int i = rnd * 256 + tid;
            int r = i >> 2, c = (i & 3) * 8;
            async16(A  + (size_t)(tm * 128 + r) * 512 + k0 + c, &As[i * 8]);
            async16(Bt + (size_t)(tn * 128 + r) * 512 + k0 + c, &Bs[i * 8]);
        }
        __syncthreads();

        h8 af[4], bf[4];
#pragma unroll
        for (int mi = 0; mi < 4; ++mi)
            af[mi] = *(const h8*)&As[(m_base + mi * 16 + l16) * 32 + quad * 8];
#pragma unroll
        for (int ni = 0; ni < 4; ++ni)
            bf[ni] = *(const h8*)&Bs[(n_base + ni * 16 + l16) * 32 + quad * 8];
#pragma unroll
        for (int mi = 0; mi < 4; ++mi)
#pragma unroll
            for (int ni = 0; ni < 4; ++ni)
                acc[mi][ni] = __builtin_amdgcn_mfma_f32_16x16x32_f16(
                    af[mi], bf[ni], acc[mi][ni], 0, 0, 0);
        __syncthreads();
    }

#pragma unroll
    for (int mi = 0; mi < 4; ++mi)
#pragma unroll
        for (int ni = 0; ni < 4; ++ni) {
            int row0 = tm * 128 + m_base + mi * 16 + quad * 4;
            int col  = tn * 128 + n_base + ni * 16 + l16;
            float bias = bp[col];
#pragma unroll
            for (int r = 0; r < 4; ++r) {
                int row = row0 + r;
                int bsq = row >> 4, t = row & 15;
                int b = bsq >> 8, s = bsq & 255;
                size_t off = (t < 8)
                    ? (VP_BASE + (size_t)((b * 8 + t) * SS + s) * DD + col)
                    : (VF_BASE + (size_t)((b * 8 + t - 8) * SS + s) * DD + col);
                out[off] = acc[mi][ni][r] + bias;
            }
        }
}

// ---------------------------------------------------------------------------
// a-rows: mean over S (reads dense attna) + fp32 projection, 64 blocks.
// ---------------------------------------------------------------------------
__global__ __launch_bounds__(256)
void proj_a_kernel(const _Float16* __restrict__ attna, const float* __restrict__ Wp,
                   const float* __restrict__ bp, float* __restrict__ out) {
    __shared__ float arow[DD];
    const int r = blockIdx.x;            // 0..63
    const int b = r >> 4, t = r & 15;
    const int tid = threadIdx.x;

    float acc0 = 0.f, acc1 = 0.f;
    for (int s = 0; s < SS; ++s) {
        h2 v = *(const h2*)&attna[((size_t)((b * SS + s) * 16 + t)) * DD + tid * 2];
        acc0 += (float)v.x;
        acc1 += (float)v.y;
    }
    arow[tid * 2]     = acc0 * (1.0f / (float)SS);
    arow[tid * 2 + 1] = acc1 * (1.0f / (float)SS);
    __syncthreads();

    for (int jj = 0; jj < 2; ++jj) {
        int j = jj * 256 + tid;
        float acc = bp[j];
        for (int k = 0; k < DD; ++k) acc += arow[k] * Wp[k * DD + j];
        size_t off = (t < 8) ? (AP_BASE + (size_t)(b * 8 + t) * DD + j)
                             : (AF_BASE + (size_t)(b * 8 + (t - 8)) * DD + j);
        out[off] = acc;
    }
}

// ---------------------------------------------------------------------------
extern "C" void kernel_launch(void* const* d_in, const int* in_sizes, int n_in,
                              void* d_out, int out_size, void* d_ws, size_t ws_size,
                              hipStream_t stream) {
    const float* v_p  = (const float*)d_in[0];
    const float* v_f  = (const float*)d_in[1];
    const float* a_p  = (const float*)d_in[2];
    const float* a_f  = (const float*)d_in[3];
    const float* Wqkv = (const float*)d_in[4];
    const float* Wp   = (const float*)d_in[5];
    const float* bp   = (const float*)d_in[6];
    float* out = (float*)d_out;

    // Workspace layout (~86.6 MB). attna ALIASES tok: tok is dead after
    // gemm_qkv_kernel, attna is written only in attn5_kernel (later on stream).
    char* w = (char*)d_ws;
    _Float16* tok   = (_Float16*)w;  w += (size_t)MPAD * DD * 2;    // 16.9 MB
    _Float16* qkv   = (_Float16*)w;  w += (size_t)MPAD * W3 * 2;    // 50.7 MB
    _Float16* attnv = (_Float16*)w;  w += (size_t)16384 * DD * 2;   // 16.8 MB
    _Float16* Wt    = (_Float16*)w;  w += (size_t)W3 * DD * 2;      //  1.6 MB
    _Float16* Wpt   = (_Float16*)w;  w += (size_t)DD * DD * 2;      //  0.5 MB
    _Float16* attna = tok;                                          // alias

    conv_kernel<<<8480, 256, 0, stream>>>(v_p, v_f, a_p, a_f, Wqkv, Wp,
                                          tok, Wt, Wpt);
    gemm_qkv_kernel<<<129 * 6, 256, 0, stream>>>(tok, Wt, qkv);
    attn5_kernel<<<2048, 256, 0, stream>>>(qkv, attnv, attna);
    gemm_proj_kernel<<<512, 256, 0, stream>>>(attnv, Wpt, bp, out);
    proj_a_kernel<<<64, 256, 0, stream>>>(attna, Wp, bp, out);
}